// Round 5
// baseline (144.806 us; speedup 1.0000x reference)
//
#include <hip/hip_runtime.h>
#include <hip/hip_cooperative_groups.h>

namespace cg = cooperative_groups;

#define LN_EPS 1e-5f

__device__ __forceinline__ float dot8(float4 a0, float4 a1, float4 b0, float4 b1) {
    return a0.x * b0.x + a0.y * b0.y + a0.z * b0.z + a0.w * b0.w +
           a1.x * b1.x + a1.y * b1.y + a1.z * b1.z + a1.w * b1.w;
}

// ---------------------------------------------------------------------------
// Fused cooperative kernel: 512 blocks x 512 threads, LDS 30.2 KB/block so
// 2 blocks/CU co-residency holds even under 64 KB/CU LDS accounting (the
// round-4 failure: 38.7 KB -> 1 block/CU -> coop launch rejected -> zeros).
// Residual x recomputed in phase 1 out-proj instead of staged in LDS.
// ---------------------------------------------------------------------------
__global__ __launch_bounds__(512, 4) void k_fused(
    const float* __restrict__ ctcf, const float* __restrict__ hac,
    const float* __restrict__ me1,  const float* __restrict__ me3,
    const float* __restrict__ ew,   const float* __restrict__ eb,
    const float* __restrict__ pe,
    const float* __restrict__ riw,  const float* __restrict__ rib,
    const float* __restrict__ row_w,const float* __restrict__ row_b,
    const float* __restrict__ rlg,  const float* __restrict__ rlb,
    const float* __restrict__ ciw,  const float* __restrict__ cib,
    const float* __restrict__ cow,  const float* __restrict__ cob,
    const float* __restrict__ clg,  const float* __restrict__ clb,
    const float* __restrict__ pw,   const float* __restrict__ pb,
    const float* __restrict__ pg,   const float* __restrict__ pbt,
    float* msaR, float* mbuf, float* nbuf, float* out)
{
    __shared__ float smem[7552];     // 30.2 KB, overlaid per phase
    const int bx  = blockIdx.x;      // 0..511
    const int tid = threadIdx.x;     // 0..511
    cg::grid_group grid = cg::this_grid();

    // =====================================================================
    // Phase 1: row attention. block = (b, s, query-half)
    // =====================================================================
    {
        float* sqkv = smem;          // [64*100], rows 16B-aligned
        float* so   = smem + 6400;   // [32][36], rows 16B-aligned

        const int qh = bx & 1, s = (bx >> 1) & 3, b = bx >> 3;
        const int qbase = qh * 32;
        const float* chip = (s == 0) ? ctcf : (s == 1) ? hac : (s == 2) ? me1 : me3;
        const int l   = tid & 63;
        const int cgi = __builtin_amdgcn_readfirstlane(tid >> 6);  // 0..7 uniform

        // fused embed straight into registers
        float xr[32];
        {
            const float cv = chip[b * 64 + l];
            const float4* pe4 = (const float4*)&pe[l * 32];
            const float4* ew4 = (const float4*)ew;
            const float4* eb4 = (const float4*)eb;
#pragma unroll
            for (int c4 = 0; c4 < 8; ++c4) {
                float4 pv = pe4[c4], e = ew4[c4], bb = eb4[c4];
                xr[c4 * 4 + 0] = cv * e.x + bb.x + pv.x;
                xr[c4 * 4 + 1] = cv * e.y + bb.y + pv.y;
                xr[c4 * 4 + 2] = cv * e.z + bb.z + pv.z;
                xr[c4 * 4 + 3] = cv * e.w + bb.w + pv.w;
            }
        }

        // QKV: contiguous 12-col chunk per wave -> 3 ds_write_b128
        {
            const int cc0 = cgi * 12;
            float acc[12];
#pragma unroll
            for (int ii = 0; ii < 12; ++ii) acc[ii] = rib[cc0 + ii];
#pragma unroll
            for (int ii = 0; ii < 12; ++ii) {
                const float4* wr4 = (const float4*)&riw[(cc0 + ii) * 32];
#pragma unroll
                for (int c4 = 0; c4 < 8; ++c4) {
                    float4 wv = wr4[c4];
                    acc[ii] += xr[c4 * 4 + 0] * wv.x + xr[c4 * 4 + 1] * wv.y +
                               xr[c4 * 4 + 2] * wv.z + xr[c4 * 4 + 3] * wv.w;
                }
            }
            float* dst = &sqkv[l * 100 + cc0];
            *(float4*)(dst + 0) = make_float4(acc[0], acc[1], acc[2],  acc[3]);
            *(float4*)(dst + 4) = make_float4(acc[4], acc[5], acc[6],  acc[7]);
            *(float4*)(dst + 8) = make_float4(acc[8], acc[9], acc[10], acc[11]);
        }
        __syncthreads();

        // attention, two-pass: thread (h = tid>>7, q = (tid>>2)&31, kc = tid&3)
        {
            const int h  = tid >> 7;
            const int q  = (tid >> 2) & 31;
            const int kc = tid & 3;
            const int lq = qbase + q;
            const float4* qp = (const float4*)&sqkv[lq * 100 + h * 8];
            float4 q0 = qp[0], q1 = qp[1];
            const float scale = 0.35355339059327373f;  // 1/sqrt(8)

            float sc[16];
#pragma unroll
            for (int jj = 0; jj < 16; ++jj) {
                const int j = kc * 16 + ((jj + kc) & 15);   // bank-staggered
                const float4* kp = (const float4*)&sqkv[j * 100 + 32 + h * 8];
                sc[jj] = dot8(q0, q1, kp[0], kp[1]) * scale;
            }
            float m0 = fmaxf(fmaxf(fmaxf(sc[0], sc[1]),  fmaxf(sc[2], sc[3])),
                             fmaxf(fmaxf(sc[4], sc[5]),  fmaxf(sc[6], sc[7])));
            float m1 = fmaxf(fmaxf(fmaxf(sc[8], sc[9]),  fmaxf(sc[10], sc[11])),
                             fmaxf(fmaxf(sc[12], sc[13]), fmaxf(sc[14], sc[15])));
            float mx = fmaxf(m0, m1);
            mx = fmaxf(mx, __shfl_xor(mx, 1, 64));
            mx = fmaxf(mx, __shfl_xor(mx, 2, 64));

            float den = 0.f, a[8];
#pragma unroll
            for (int dd = 0; dd < 8; ++dd) a[dd] = 0.f;
#pragma unroll
            for (int jj = 0; jj < 16; ++jj) {
                const int j = kc * 16 + ((jj + kc) & 15);
                float wgt = __expf(sc[jj] - mx);
                den += wgt;
                const float4* vp = (const float4*)&sqkv[j * 100 + 64 + h * 8];
                float4 v0 = vp[0], v1 = vp[1];
                a[0] += wgt * v0.x;  a[1] += wgt * v0.y;
                a[2] += wgt * v0.z;  a[3] += wgt * v0.w;
                a[4] += wgt * v1.x;  a[5] += wgt * v1.y;
                a[6] += wgt * v1.z;  a[7] += wgt * v1.w;
            }
#pragma unroll
            for (int off = 1; off <= 2; off <<= 1) {
                den += __shfl_xor(den, off, 64);
#pragma unroll
                for (int dd = 0; dd < 8; ++dd) a[dd] += __shfl_xor(a[dd], off, 64);
            }
            float inv = 1.f / den;
            float r0, r1;
            if      (kc == 0) { r0 = a[0]; r1 = a[1]; }
            else if (kc == 1) { r0 = a[2]; r1 = a[3]; }
            else if (kc == 2) { r0 = a[4]; r1 = a[5]; }
            else              { r0 = a[6]; r1 = a[7]; }
            so[q * 36 + h * 8 + kc * 2 + 0] = r0 * inv;
            so[q * 36 + h * 8 + kc * 2 + 1] = r1 * inv;
        }
        __syncthreads();

        // out proj + residual (residual recomputed: no sx tile in LDS)
        {
            const int lq2 = tid & 31;
            const int cB  = tid >> 5;        // 0..15
            const int lg  = qbase + lq2;     // global row 0..63
            const float cvr = chip[b * 64 + lg];
            float orow[32];
            const float4* sop = (const float4*)&so[lq2 * 36];
#pragma unroll
            for (int k4 = 0; k4 < 8; ++k4) {
                float4 t = sop[k4];
                orow[k4 * 4 + 0] = t.x;  orow[k4 * 4 + 1] = t.y;
                orow[k4 * 4 + 2] = t.z;  orow[k4 * 4 + 3] = t.w;
            }
#pragma unroll
            for (int i = 0; i < 2; ++i) {
                int c = cB + i * 16;
                const float4* wr4 = (const float4*)&row_w[c * 32];
                float acc = row_b[c] + (cvr * ew[c] + eb[c] + pe[lg * 32 + c]);
#pragma unroll
                for (int k4 = 0; k4 < 8; ++k4) {
                    float4 wv = wr4[k4];
                    acc += orow[k4 * 4 + 0] * wv.x + orow[k4 * 4 + 1] * wv.y +
                           orow[k4 * 4 + 2] * wv.z + orow[k4 * 4 + 3] * wv.w;
                }
                sqkv[lq2 * 100 + c] = acc;
            }
        }
        __syncthreads();

        // LN + write via 32-lane shuffle reductions
        {
            const int c = tid & 31;
#pragma unroll
            for (int p = 0; p < 2; ++p) {
                int r = p * 16 + (tid >> 5);           // 0..31 local row
                float v = sqkv[r * 100 + c];
                float s1 = v;
#pragma unroll
                for (int off = 16; off >= 1; off >>= 1) s1 += __shfl_xor(s1, off, 64);
                float mu = s1 * (1.f / 32.f);
                float d = v - mu;
                float s2 = d * d;
#pragma unroll
                for (int off = 16; off >= 1; off >>= 1) s2 += __shfl_xor(s2, off, 64);
                float rstd = rsqrtf(s2 * (1.f / 32.f) + LN_EPS);
                msaR[((b * 4 + s) * 64 + qbase + r) * 32 + c] =
                    d * rstd * rlg[c] + rlb[c];
            }
        }
    }
    grid.sync();

    // =====================================================================
    // Phase 2: column attention. block = (b, 8-bin chunk) -> 32 rows
    // =====================================================================
    {
        float* sx2   = smem;          // [32][33]
        float* sqkv2 = smem + 1056;   // [32*100]
        float* so2   = smem + 4256;   // [32][36]

        const int b  = bx >> 3;
        const int l0 = (bx & 7) * 8;

        for (int n = tid; n < 1024; n += 512) {
            int r = n >> 5, c = n & 31;
            int lo = r >> 2, s = r & 3;
            sx2[r * 33 + c] = msaR[((b * 4 + s) * 64 + l0 + lo) * 32 + c];
        }
        __syncthreads();

        // qkv: 32 rows x 96 cols, 6 outputs/thread
        {
            const int rr = tid & 31;
            const int cg2 = tid >> 5;        // 0..15
            float xr[32];
#pragma unroll
            for (int c = 0; c < 32; ++c) xr[c] = sx2[rr * 33 + c];
#pragma unroll
            for (int i = 0; i < 6; ++i) {
                int cc = i * 16 + cg2;
                const float4* wr4 = (const float4*)&ciw[cc * 32];
                float acc = cib[cc];
#pragma unroll
                for (int c4 = 0; c4 < 8; ++c4) {
                    float4 wv = wr4[c4];
                    acc += xr[c4 * 4 + 0] * wv.x + xr[c4 * 4 + 1] * wv.y +
                           xr[c4 * 4 + 2] * wv.z + xr[c4 * 4 + 3] * wv.w;
                }
                sqkv2[rr * 100 + cc] = acc;
            }
        }
        __syncthreads();

        // attention over 4 tracks: 128 units (lo, h, ia)
        if (tid < 128) {
            const int lo = tid >> 4, h = (tid >> 2) & 3, ia = tid & 3;
            const float scale = 0.35355339059327373f;
            const float4* qp = (const float4*)&sqkv2[(lo * 4 + ia) * 100 + h * 8];
            float4 q0 = qp[0], q1 = qp[1];
            float sc[4];
            float mx = -1e30f;
#pragma unroll
            for (int jj = 0; jj < 4; ++jj) {
                const float4* kp = (const float4*)&sqkv2[(lo * 4 + jj) * 100 + 32 + h * 8];
                sc[jj] = dot8(q0, q1, kp[0], kp[1]) * scale;
                mx = fmaxf(mx, sc[jj]);
            }
            float den = 0.f;
#pragma unroll
            for (int jj = 0; jj < 4; ++jj) { sc[jj] = __expf(sc[jj] - mx); den += sc[jj]; }
            float inv = 1.f / den;
            float a[8];
#pragma unroll
            for (int dd = 0; dd < 8; ++dd) a[dd] = 0.f;
#pragma unroll
            for (int jj = 0; jj < 4; ++jj) {
                const float4* vp = (const float4*)&sqkv2[(lo * 4 + jj) * 100 + 64 + h * 8];
                float4 v0 = vp[0], v1 = vp[1];
                float wgt = sc[jj];
                a[0] += wgt * v0.x;  a[1] += wgt * v0.y;
                a[2] += wgt * v0.z;  a[3] += wgt * v0.w;
                a[4] += wgt * v1.x;  a[5] += wgt * v1.y;
                a[6] += wgt * v1.z;  a[7] += wgt * v1.w;
            }
#pragma unroll
            for (int dd = 0; dd < 8; ++dd) so2[(lo * 4 + ia) * 36 + h * 8 + dd] = a[dd] * inv;
        }
        __syncthreads();

        // out proj + residual (2 outputs/thread)
        {
            const int r2 = tid & 31;
            const int cB = tid >> 5;
            float orow[32];
            const float4* sop = (const float4*)&so2[r2 * 36];
#pragma unroll
            for (int k4 = 0; k4 < 8; ++k4) {
                float4 t = sop[k4];
                orow[k4 * 4 + 0] = t.x;  orow[k4 * 4 + 1] = t.y;
                orow[k4 * 4 + 2] = t.z;  orow[k4 * 4 + 3] = t.w;
            }
#pragma unroll
            for (int i = 0; i < 2; ++i) {
                int c = cB + i * 16;
                const float4* wr4 = (const float4*)&cow[c * 32];
                float acc = cob[c] + sx2[r2 * 33 + c];
#pragma unroll
                for (int k4 = 0; k4 < 8; ++k4) {
                    float4 wv = wr4[k4];
                    acc += orow[k4 * 4 + 0] * wv.x + orow[k4 * 4 + 1] * wv.y +
                           orow[k4 * 4 + 2] * wv.z + orow[k4 * 4 + 3] * wv.w;
                }
                sqkv2[r2 * 100 + c] = acc;
            }
        }
        __syncthreads();

        // LN normalize per row (pre-gamma) into so2
        {
            const int c = tid & 31;
#pragma unroll
            for (int p = 0; p < 2; ++p) {
                int r = p * 16 + (tid >> 5);
                float v = sqkv2[r * 100 + c];
                float s1 = v;
#pragma unroll
                for (int off = 16; off >= 1; off >>= 1) s1 += __shfl_xor(s1, off, 64);
                float mu = s1 * (1.f / 32.f);
                float d = v - mu;
                float s2 = d * d;
#pragma unroll
                for (int off = 16; off >= 1; off >>= 1) s2 += __shfl_xor(s2, off, 64);
                float rstd = rsqrtf(s2 * (1.f / 32.f) + LN_EPS);
                so2[r * 36 + c] = d * rstd;
            }
        }
        __syncthreads();

        // track mean (gamma/beta folded) + row norm via shuffle: 8 lo x 32 c
        if (tid < 256) {
            const int lo = tid >> 5, c = tid & 31;
            float mval = 0.25f * (so2[(lo * 4 + 0) * 36 + c] + so2[(lo * 4 + 1) * 36 + c] +
                                  so2[(lo * 4 + 2) * 36 + c] + so2[(lo * 4 + 3) * 36 + c]) *
                         clg[c] + clb[c];
            mbuf[(b * 64 + l0 + lo) * 32 + c] = mval;
            float q2 = mval * mval;
#pragma unroll
            for (int off = 16; off >= 1; off >>= 1) q2 += __shfl_xor(q2, off, 64);
            if (c == 0) nbuf[b * 64 + l0 + lo] = sqrtf(q2);
        }
    }
    grid.sync();

    // =====================================================================
    // Phase 3: pair features. block = (b, 8-row i-chunk); wave w -> il = w
    // =====================================================================
    {
        float* smj = smem;            // [64][36]
        float* sT  = smem + 2304;     // [8*520]
        float* snj = smem + 6464;     // [64]
        float* sb  = smem + 6528;     // [16]
        float* sg  = smem + 6544;     // [16]
        float* sbt = smem + 6560;     // [16]

        const int b  = bx >> 3;
        const int i0 = (bx & 7) * 8;
        const int lane = tid & 63, w = tid >> 6;   // w = 0..7

        // preload this thread's pw rem-row (rem = tid = cp*32+d)
        const float* pwp = pw + (tid >> 5) * 1024 + (tid & 31);
        float w0[32];
#pragma unroll
        for (int c = 0; c < 32; ++c) w0[c] = pwp[c * 32];

        const float* mb = mbuf + b * 2048;
        for (int n = tid; n < 2048; n += 512) smj[(n >> 5) * 36 + (n & 31)] = mb[n];
        if (tid < 64) snj[tid] = nbuf[b * 64 + tid];
        if (tid < 16) { sb[tid] = pb[tid]; sg[tid] = pg[tid]; sbt[tid] = pbt[tid]; }
        __syncthreads();

        // T phase: thread computes T[il][tid] for il = 0..7
#pragma unroll
        for (int il = 0; il < 8; ++il) {
            const float4* mr4 = (const float4*)&smj[(i0 + il) * 36];  // b128 bcast
            float a0 = 0.f;
#pragma unroll
            for (int c4 = 0; c4 < 8; ++c4) {
                float4 mv = mr4[c4];
                a0 += mv.x * w0[c4 * 4 + 0] + mv.y * w0[c4 * 4 + 1] +
                      mv.z * w0[c4 * 4 + 2] + mv.w * w0[c4 * 4 + 3];
            }
            sT[il * 520 + tid] = a0;
        }
        __syncthreads();

        // out phase: lane = j; wave w handles il = w
        const int j = lane;
        float mj[32];
        {
            const float4* mjp = (const float4*)&smj[j * 36];
#pragma unroll
            for (int d4 = 0; d4 < 8; ++d4) {
                float4 t = mjp[d4];
                mj[d4 * 4 + 0] = t.x;  mj[d4 * 4 + 1] = t.y;
                mj[d4 * 4 + 2] = t.z;  mj[d4 * 4 + 3] = t.w;
            }
        }
        const float nj = snj[j];
        const int il = w;
        const int ig = i0 + il;
        const float invn = 1.f / fmaxf(snj[ig] * nj, 1e-6f);
        float f[16];
#pragma unroll
        for (int cp = 0; cp < 16; ++cp) {
            const float4* tr = (const float4*)&sT[il * 520 + cp * 32]; // b128 bcast
            float acc = 0.f;
#pragma unroll
            for (int d4 = 0; d4 < 8; ++d4) {
                float4 tv = tr[d4];
                acc += tv.x * mj[d4 * 4 + 0] + tv.y * mj[d4 * 4 + 1] +
                       tv.z * mj[d4 * 4 + 2] + tv.w * mj[d4 * 4 + 3];
            }
            f[cp] = acc * invn + sb[cp];
        }
        float mu = 0.f;
#pragma unroll
        for (int cp = 0; cp < 16; ++cp) mu += f[cp];
        mu *= (1.f / 16.f);
        float var = 0.f;
#pragma unroll
        for (int cp = 0; cp < 16; ++cp) { float d = f[cp] - mu; var += d * d; }
        var *= (1.f / 16.f);
        const float rstd = rsqrtf(var + LN_EPS);
#pragma unroll
        for (int cp = 0; cp < 16; ++cp) {
            float v = (f[cp] - mu) * rstd * sg[cp] + sbt[cp];
            float sl = v / (1.f + __expf(-v));
            out[((b * 16 + cp) * 64 + ig) * 64 + j] = sl;
        }
    }
}

// ===========================================================================
// Fallback path: proven round-3 three-kernel pipeline (144.2 us, passed).
// Used if cooperative co-residency is unavailable.
// ===========================================================================
__global__ __launch_bounds__(512, 4) void k_row(
    const float* __restrict__ ctcf, const float* __restrict__ hac,
    const float* __restrict__ me1,  const float* __restrict__ me3,
    const float* __restrict__ ew,   const float* __restrict__ eb,
    const float* __restrict__ pe,
    const float* __restrict__ w_in, const float* __restrict__ b_in,
    const float* __restrict__ w_out,const float* __restrict__ b_out,
    const float* __restrict__ ln_g, const float* __restrict__ ln_b,
    float* __restrict__ msaR)
{
    __shared__ float sx[64][33];
    __shared__ float sqkv[64 * 100];
    __shared__ float so[32][33];

    const int blk = blockIdx.x;
    const int qh  = blk & 1;
    const int s   = (blk >> 1) & 3;
    const int b   = blk >> 3;
    const int qbase = qh * 32;
    const int tid = threadIdx.x;

    const float* chip = (s == 0) ? ctcf : (s == 1) ? hac : (s == 2) ? me1 : me3;

    const int l  = tid & 63;
    const int cg = __builtin_amdgcn_readfirstlane(tid >> 6);

    float xr[32];
    {
        const float cv = chip[b * 64 + l];
        const float4* pe4 = (const float4*)&pe[l * 32];
        const float4* ew4 = (const float4*)ew;
        const float4* eb4 = (const float4*)eb;
#pragma unroll
        for (int c4 = 0; c4 < 8; ++c4) {
            float4 pv = pe4[c4], e = ew4[c4], bb = eb4[c4];
            xr[c4 * 4 + 0] = cv * e.x + bb.x + pv.x;
            xr[c4 * 4 + 1] = cv * e.y + bb.y + pv.y;
            xr[c4 * 4 + 2] = cv * e.z + bb.z + pv.z;
            xr[c4 * 4 + 3] = cv * e.w + bb.w + pv.w;
        }
    }
    if (cg == 0) {
#pragma unroll
        for (int c = 0; c < 32; ++c) sx[l][c] = xr[c];
    }

#pragma unroll
    for (int i = 0; i < 12; ++i) {
        const int cc = i * 8 + cg;
        const float4* wr4 = (const float4*)&w_in[cc * 32];
        float acc = b_in[cc];
#pragma unroll
        for (int c4 = 0; c4 < 8; ++c4) {
            float4 wv = wr4[c4];
            acc += xr[c4 * 4 + 0] * wv.x + xr[c4 * 4 + 1] * wv.y +
                   xr[c4 * 4 + 2] * wv.z + xr[c4 * 4 + 3] * wv.w;
        }
        sqkv[l * 100 + cc] = acc;
    }
    __syncthreads();

    {
        const int h  = tid >> 7;
        const int q  = (tid >> 2) & 31;
        const int kc = tid & 3;
        const int lq = qbase + q;
        const float4* qp = (const float4*)&sqkv[lq * 100 + h * 8];
        float4 q0 = qp[0], q1 = qp[1];
        const float scale = 0.35355339059327373f;

        float sc[16];
#pragma unroll
        for (int jj = 0; jj < 16; ++jj) {
            const int j = kc * 16 + ((jj + kc) & 15);
            const float4* kp = (const float4*)&sqkv[j * 100 + 32 + h * 8];
            sc[jj] = dot8(q0, q1, kp[0], kp[1]) * scale;
        }
        float m0 = fmaxf(fmaxf(fmaxf(sc[0], sc[1]),  fmaxf(sc[2], sc[3])),
                         fmaxf(fmaxf(sc[4], sc[5]),  fmaxf(sc[6], sc[7])));
        float m1 = fmaxf(fmaxf(fmaxf(sc[8], sc[9]),  fmaxf(sc[10], sc[11])),
                         fmaxf(fmaxf(sc[12], sc[13]), fmaxf(sc[14], sc[15])));
        float mx = fmaxf(m0, m1);
        mx = fmaxf(mx, __shfl_xor(mx, 1, 64));
        mx = fmaxf(mx, __shfl_xor(mx, 2, 64));

        float den = 0.f, a[8];
#pragma unroll
        for (int dd = 0; dd < 8; ++dd) a[dd] = 0.f;
#pragma unroll
        for (int jj = 0; jj < 16; ++jj) {
            const int j = kc * 16 + ((jj + kc) & 15);
            float w = __expf(sc[jj] - mx);
            den += w;
            const float4* vp = (const float4*)&sqkv[j * 100 + 64 + h * 8];
            float4 v0 = vp[0], v1 = vp[1];
            a[0] += w * v0.x;  a[1] += w * v0.y;
            a[2] += w * v0.z;  a[3] += w * v0.w;
            a[4] += w * v1.x;  a[5] += w * v1.y;
            a[6] += w * v1.z;  a[7] += w * v1.w;
        }
#pragma unroll
        for (int off = 1; off <= 2; off <<= 1) {
            den += __shfl_xor(den, off, 64);
#pragma unroll
            for (int dd = 0; dd < 8; ++dd) a[dd] += __shfl_xor(a[dd], off, 64);
        }
        float inv = 1.f / den;
        float r0, r1;
        if      (kc == 0) { r0 = a[0]; r1 = a[1]; }
        else if (kc == 1) { r0 = a[2]; r1 = a[3]; }
        else if (kc == 2) { r0 = a[4]; r1 = a[5]; }
        else              { r0 = a[6]; r1 = a[7]; }
        so[q][h * 8 + kc * 2 + 0] = r0 * inv;
        so[q][h * 8 + kc * 2 + 1] = r1 * inv;
    }
    __syncthreads();

    {
        const int lq2 = tid & 31;
        const int cB  = tid >> 5;
        float orow[32];
#pragma unroll
        for (int k = 0; k < 32; ++k) orow[k] = so[lq2][k];
#pragma unroll
        for (int i = 0; i < 2; ++i) {
            int c = cB + i * 16;
            const float4* wr4 = (const float4*)&w_out[c * 32];
            float acc = b_out[c] + sx[qbase + lq2][c];
#pragma unroll
            for (int k4 = 0; k4 < 8; ++k4) {
                float4 wv = wr4[k4];
                acc += orow[k4 * 4 + 0] * wv.x + orow[k4 * 4 + 1] * wv.y +
                       orow[k4 * 4 + 2] * wv.z + orow[k4 * 4 + 3] * wv.w;
            }
            sqkv[lq2 * 100 + c] = acc;
        }
    }
    __syncthreads();

    {
        const int c = tid & 31;
#pragma unroll
        for (int p = 0; p < 2; ++p) {
            int r = p * 16 + (tid >> 5);
            float v = sqkv[r * 100 + c];
            float s1 = v;
#pragma unroll
            for (int off = 16; off >= 1; off >>= 1) s1 += __shfl_xor(s1, off, 64);
            float mu = s1 * (1.f / 32.f);
            float d = v - mu;
            float s2 = d * d;
#pragma unroll
            for (int off = 16; off >= 1; off >>= 1) s2 += __shfl_xor(s2, off, 64);
            float rstd = rsqrtf(s2 * (1.f / 32.f) + LN_EPS);
            msaR[((b * 4 + s) * 64 + qbase + r) * 32 + c] = d * rstd * ln_g[c] + ln_b[c];
        }
    }
}

__global__ __launch_bounds__(256, 4) void k_col(
    const float* __restrict__ msaR,
    const float* __restrict__ w_in, const float* __restrict__ b_in,
    const float* __restrict__ w_out,const float* __restrict__ b_out,
    const float* __restrict__ ln_g, const float* __restrict__ ln_b,
    float* __restrict__ m_out, float* __restrict__ nrm_out)
{
    __shared__ float sx[16][33];
    __shared__ float sqkv[16 * 100];
    __shared__ float so[16][33];

    const int bx = blockIdx.x;
    const int b  = bx >> 4;
    const int l0 = (bx & 15) * 4;
    const int tid = threadIdx.x;

    for (int n = tid; n < 512; n += 256) {
        int r = n >> 5, c = n & 31;
        int lo = r >> 2, s = r & 3;
        sx[r][c] = msaR[((b * 4 + s) * 64 + l0 + lo) * 32 + c];
    }
    __syncthreads();

    {
        const int rr = tid & 15;
        const int cg = tid >> 4;
        float xr[32];
#pragma unroll
        for (int c = 0; c < 32; ++c) xr[c] = sx[rr][c];
#pragma unroll
        for (int i = 0; i < 6; ++i) {
            int cc = i * 16 + cg;
            const float4* wr4 = (const float4*)&w_in[cc * 32];
            float acc = b_in[cc];
#pragma unroll
            for (int c4 = 0; c4 < 8; ++c4) {
                float4 wv = wr4[c4];
                acc += xr[c4 * 4 + 0] * wv.x + xr[c4 * 4 + 1] * wv.y +
                       xr[c4 * 4 + 2] * wv.z + xr[c4 * 4 + 3] * wv.w;
            }
            sqkv[rr * 100 + cc] = acc;
        }
    }
    __syncthreads();

    if (tid < 64) {
        const int lo = tid >> 4, h = (tid >> 2) & 3, ia = tid & 3;
        const float scale = 0.35355339059327373f;
        const float4* qp = (const float4*)&sqkv[(lo * 4 + ia) * 100 + h * 8];
        float4 q0 = qp[0], q1 = qp[1];
        float sc[4];
        float mx = -1e30f;
#pragma unroll
        for (int jj = 0; jj < 4; ++jj) {
            const float4* kp = (const float4*)&sqkv[(lo * 4 + jj) * 100 + 32 + h * 8];
            sc[jj] = dot8(q0, q1, kp[0], kp[1]) * scale;
            mx = fmaxf(mx, sc[jj]);
        }
        float den = 0.f;
#pragma unroll
        for (int jj = 0; jj < 4; ++jj) { sc[jj] = __expf(sc[jj] - mx); den += sc[jj]; }
        float inv = 1.f / den;
        float a[8];
#pragma unroll
        for (int dd = 0; dd < 8; ++dd) a[dd] = 0.f;
#pragma unroll
        for (int jj = 0; jj < 4; ++jj) {
            const float4* vp = (const float4*)&sqkv[(lo * 4 + jj) * 100 + 64 + h * 8];
            float4 v0 = vp[0], v1 = vp[1];
            float wgt = sc[jj];
            a[0] += wgt * v0.x;  a[1] += wgt * v0.y;
            a[2] += wgt * v0.z;  a[3] += wgt * v0.w;
            a[4] += wgt * v1.x;  a[5] += wgt * v1.y;
            a[6] += wgt * v1.z;  a[7] += wgt * v1.w;
        }
#pragma unroll
        for (int dd = 0; dd < 8; ++dd) so[lo * 4 + ia][h * 8 + dd] = a[dd] * inv;
    }
    __syncthreads();

    {
        const int r2 = tid & 15;
        const int cB = tid >> 4;
        float orow[32];
#pragma unroll
        for (int k = 0; k < 32; ++k) orow[k] = so[r2][k];
#pragma unroll
        for (int i = 0; i < 2; ++i) {
            int c = cB + i * 16;
            const float4* wr4 = (const float4*)&w_out[c * 32];
            float acc = b_out[c] + sx[r2][c];
#pragma unroll
            for (int k4 = 0; k4 < 8; ++k4) {
                float4 wv = wr4[k4];
                acc += orow[k4 * 4 + 0] * wv.x + orow[k4 * 4 + 1] * wv.y +
                       orow[k4 * 4 + 2] * wv.z + orow[k4 * 4 + 3] * wv.w;
            }
            sqkv[r2 * 100 + c] = acc;
        }
    }
    __syncthreads();

    {
        const int c = tid & 31;
#pragma unroll
        for (int p = 0; p < 2; ++p) {
            int r = p * 8 + (tid >> 5);
            float v = sqkv[r * 100 + c];
            float s1 = v;
#pragma unroll
            for (int off = 16; off >= 1; off >>= 1) s1 += __shfl_xor(s1, off, 64);
            float mu = s1 * (1.f / 32.f);
            float d = v - mu;
            float s2 = d * d;
#pragma unroll
            for (int off = 16; off >= 1; off >>= 1) s2 += __shfl_xor(s2, off, 64);
            float rstd = rsqrtf(s2 * (1.f / 32.f) + LN_EPS);
            so[r][c] = d * rstd;
        }
    }
    __syncthreads();

    if (tid < 128) {
        const int lo = tid >> 5, c = tid & 31;
        float mval = 0.25f * (so[lo * 4 + 0][c] + so[lo * 4 + 1][c] +
                              so[lo * 4 + 2][c] + so[lo * 4 + 3][c]) * ln_g[c] + ln_b[c];
        m_out[(b * 64 + l0 + lo) * 32 + c] = mval;
        float q2 = mval * mval;
#pragma unroll
        for (int off = 16; off >= 1; off >>= 1) q2 += __shfl_xor(q2, off, 64);
        if (c == 0) nrm_out[b * 64 + l0 + lo] = sqrtf(q2);
    }
}

__global__ __launch_bounds__(256, 4) void k_pair(
    const float* __restrict__ m, const float* __restrict__ nrm,
    const float* __restrict__ pw, const float* __restrict__ pb,
    const float* __restrict__ pg, const float* __restrict__ pbeta,
    float* __restrict__ out)
{
    __shared__ float smj[64][36];
    __shared__ float sT[4 * 520];
    __shared__ float snj[64];
    __shared__ float sbias[16], sgam[16], sbet[16];

    const int bx = blockIdx.x;
    const int b  = bx >> 4;
    const int i0 = (bx & 15) * 4;
    const int tid = threadIdx.x;
    const int lane = tid & 63, w = tid >> 6;

    const int rem0 = tid, rem1 = tid + 256;
    const float* pw0 = pw + (rem0 >> 5) * 1024 + (rem0 & 31);
    const float* pw1 = pw + (rem1 >> 5) * 1024 + (rem1 & 31);
    float w0[32], w1[32];
#pragma unroll
    for (int c = 0; c < 32; ++c) { w0[c] = pw0[c * 32]; w1[c] = pw1[c * 32]; }

    const float* mb = m + b * 2048;
    for (int n = tid; n < 2048; n += 256) smj[n >> 5][n & 31] = mb[n];
    if (tid < 64) snj[tid] = nrm[b * 64 + tid];
    if (tid < 16) {
        sbias[tid] = pb[tid];
        sgam[tid]  = pg[tid];
        sbet[tid]  = pbeta[tid];
    }
    __syncthreads();

#pragma unroll
    for (int il = 0; il < 4; ++il) {
        const float4* mr4 = (const float4*)&smj[i0 + il][0];
        float a0 = 0.f, a1 = 0.f;
#pragma unroll
        for (int c4 = 0; c4 < 8; ++c4) {
            float4 mv = mr4[c4];
            a0 += mv.x * w0[c4 * 4 + 0] + mv.y * w0[c4 * 4 + 1] +
                  mv.z * w0[c4 * 4 + 2] + mv.w * w0[c4 * 4 + 3];
            a1 += mv.x * w1[c4 * 4 + 0] + mv.y * w1[c4 * 4 + 1] +
                  mv.z * w1[c4 * 4 + 2] + mv.w * w1[c4 * 4 + 3];
        }
        sT[il * 520 + rem0] = a0;
        sT[il * 520 + rem1] = a1;
    }
    __syncthreads();

    const int j = lane;
    float mj[32];
    {
        const float4* mjp = (const float4*)&smj[j][0];
#pragma unroll
        for (int d4 = 0; d4 < 8; ++d4) {
            float4 t = mjp[d4];
            mj[d4 * 4 + 0] = t.x;  mj[d4 * 4 + 1] = t.y;
            mj[d4 * 4 + 2] = t.z;  mj[d4 * 4 + 3] = t.w;
        }
    }
    const float nj = snj[j];

    {
        const int il = w;
        const int ig = i0 + il;
        const float invn = 1.f / fmaxf(snj[ig] * nj, 1e-6f);
        float f[16];
#pragma unroll
        for (int cp = 0; cp < 16; ++cp) {
            const float4* tr = (const float4*)&sT[il * 520 + cp * 32];
            float acc = 0.f;
#pragma unroll
            for (int d4 = 0; d4 < 8; ++d4) {
                float4 tv = tr[d4];
                acc += tv.x * mj[d4 * 4 + 0] + tv.y * mj[d4 * 4 + 1] +
                       tv.z * mj[d4 * 4 + 2] + tv.w * mj[d4 * 4 + 3];
            }
            f[cp] = acc * invn + sbias[cp];
        }
        float mu = 0.f;
#pragma unroll
        for (int cp = 0; cp < 16; ++cp) mu += f[cp];
        mu *= (1.f / 16.f);
        float var = 0.f;
#pragma unroll
        for (int cp = 0; cp < 16; ++cp) { float d = f[cp] - mu; var += d * d; }
        var *= (1.f / 16.f);
        const float rstd = rsqrtf(var + LN_EPS);
#pragma unroll
        for (int cp = 0; cp < 16; ++cp) {
            float v = (f[cp] - mu) * rstd * sgam[cp] + sbet[cp];
            float sl = v / (1.f + __expf(-v));
            out[((b * 16 + cp) * 64 + ig) * 64 + j] = sl;
        }
    }
}

// ---------------------------------------------------------------------------
extern "C" void kernel_launch(void* const* d_in, const int* in_sizes, int n_in,
                              void* d_out, int out_size, void* d_ws, size_t ws_size,
                              hipStream_t stream) {
    const float* ctcf  = (const float*)d_in[0];
    const float* hac   = (const float*)d_in[1];
    const float* me1   = (const float*)d_in[2];
    const float* me3   = (const float*)d_in[3];
    const float* ew    = (const float*)d_in[4];
    const float* ebias = (const float*)d_in[5];
    const float* pe    = (const float*)d_in[6];
    const float* riw   = (const float*)d_in[7];
    const float* rib   = (const float*)d_in[8];
    const float* row_  = (const float*)d_in[9];
    const float* rob   = (const float*)d_in[10];
    const float* rlg   = (const float*)d_in[11];
    const float* rlb   = (const float*)d_in[12];
    const float* ciw   = (const float*)d_in[13];
    const float* cib   = (const float*)d_in[14];
    const float* cow   = (const float*)d_in[15];
    const float* cob   = (const float*)d_in[16];
    const float* clg   = (const float*)d_in[17];
    const float* clb   = (const float*)d_in[18];
    const float* pw    = (const float*)d_in[19];
    const float* pb    = (const float*)d_in[20];
    const float* pg    = (const float*)d_in[21];
    const float* pbt   = (const float*)d_in[22];

    float* outp = (float*)d_out;

    // msaR (2 MB) borrows d_out (16 MB): consumed before out writes.
    float* msaR = (float*)d_out;
    float* mbuf = (float*)d_ws;                  // 64*64*32 floats
    float* nbuf = mbuf + 64 * 64 * 32;           // 64*64 floats

    // Decide once: can 512 coop blocks be co-resident (needs 2 blocks/CU)?
    static int s_coop = -1;
    if (s_coop < 0) {
        int nb = 0;
        hipError_t e = hipOccupancyMaxActiveBlocksPerMultiprocessor(
            &nb, k_fused, 512, 0);
        s_coop = (e == hipSuccess && nb >= 2) ? 1 : 0;
    }

    if (s_coop) {
        void* args[] = {
            (void*)&ctcf, (void*)&hac, (void*)&me1, (void*)&me3,
            (void*)&ew,   (void*)&ebias, (void*)&pe,
            (void*)&riw,  (void*)&rib, (void*)&row_, (void*)&rob,
            (void*)&rlg,  (void*)&rlb,
            (void*)&ciw,  (void*)&cib, (void*)&cow, (void*)&cob,
            (void*)&clg,  (void*)&clb,
            (void*)&pw,   (void*)&pb,  (void*)&pg,  (void*)&pbt,
            (void*)&msaR, (void*)&mbuf, (void*)&nbuf, (void*)&outp
        };
        hipError_t le = hipLaunchCooperativeKernel((void*)k_fused, dim3(512),
                                                   dim3(512), args, 0, stream);
        if (le != hipSuccess) s_coop = 0;     // fall through to 3-kernel path
    }
    if (!s_coop) {
        k_row<<<512, 512, 0, stream>>>(ctcf, hac, me1, me3, ew, ebias, pe,
                                       riw, rib, row_, rob, rlg, rlb, msaR);
        k_col<<<1024, 256, 0, stream>>>(msaR, ciw, cib, cow, cob, clg, clb,
                                        mbuf, nbuf);
        k_pair<<<1024, 256, 0, stream>>>(mbuf, nbuf, pw, pb, pg, pbt, outp);
    }
}

// Round 6
// 142.721 us; speedup vs baseline: 1.0146x; 1.0146x over previous
//
#include <hip/hip_runtime.h>
#include <hip/hip_cooperative_groups.h>

namespace cg = cooperative_groups;

#define LN_EPS 1e-5f

__device__ __forceinline__ float dot8(float4 a0, float4 a1, float4 b0, float4 b1) {
    return a0.x * b0.x + a0.y * b0.y + a0.z * b0.z + a0.w * b0.w +
           a1.x * b1.x + a1.y * b1.y + a1.z * b1.z + a1.w * b1.w;
}

// ---------------------------------------------------------------------------
// k12: phases 1+2 fused (cooperative), ONE grid.sync. 512 x 512, 30.2 KB LDS
// (2 blocks/CU co-resident under 64KB accounting). Phase bodies identical to
// the round-5 verified kernel. Phase 3 split out so rocprof decomposes time.
// ---------------------------------------------------------------------------
__global__ __launch_bounds__(512, 4) void k12(
    const float* __restrict__ ctcf, const float* __restrict__ hac,
    const float* __restrict__ me1,  const float* __restrict__ me3,
    const float* __restrict__ ew,   const float* __restrict__ eb,
    const float* __restrict__ pe,
    const float* __restrict__ riw,  const float* __restrict__ rib,
    const float* __restrict__ row_w,const float* __restrict__ row_b,
    const float* __restrict__ rlg,  const float* __restrict__ rlb,
    const float* __restrict__ ciw,  const float* __restrict__ cib,
    const float* __restrict__ cow,  const float* __restrict__ cob,
    const float* __restrict__ clg,  const float* __restrict__ clb,
    float* msaR, float* mbuf, float* nbuf)
{
    __shared__ float smem[7552];     // 30.2 KB
    const int bx  = blockIdx.x;      // 0..511
    const int tid = threadIdx.x;     // 0..511
    cg::grid_group grid = cg::this_grid();

    // ================= Phase 1: row attention =================
    {
        float* sqkv = smem;          // [64*100]
        float* so   = smem + 6400;   // [32][36]

        const int qh = bx & 1, s = (bx >> 1) & 3, b = bx >> 3;
        const int qbase = qh * 32;
        const float* chip = (s == 0) ? ctcf : (s == 1) ? hac : (s == 2) ? me1 : me3;
        const int l   = tid & 63;
        const int cgi = __builtin_amdgcn_readfirstlane(tid >> 6);

        float xr[32];
        {
            const float cv = chip[b * 64 + l];
            const float4* pe4 = (const float4*)&pe[l * 32];
            const float4* ew4 = (const float4*)ew;
            const float4* eb4 = (const float4*)eb;
#pragma unroll
            for (int c4 = 0; c4 < 8; ++c4) {
                float4 pv = pe4[c4], e = ew4[c4], bb = eb4[c4];
                xr[c4 * 4 + 0] = cv * e.x + bb.x + pv.x;
                xr[c4 * 4 + 1] = cv * e.y + bb.y + pv.y;
                xr[c4 * 4 + 2] = cv * e.z + bb.z + pv.z;
                xr[c4 * 4 + 3] = cv * e.w + bb.w + pv.w;
            }
        }

        {
            const int cc0 = cgi * 12;
            float acc[12];
#pragma unroll
            for (int ii = 0; ii < 12; ++ii) acc[ii] = rib[cc0 + ii];
#pragma unroll
            for (int ii = 0; ii < 12; ++ii) {
                const float4* wr4 = (const float4*)&riw[(cc0 + ii) * 32];
#pragma unroll
                for (int c4 = 0; c4 < 8; ++c4) {
                    float4 wv = wr4[c4];
                    acc[ii] += xr[c4 * 4 + 0] * wv.x + xr[c4 * 4 + 1] * wv.y +
                               xr[c4 * 4 + 2] * wv.z + xr[c4 * 4 + 3] * wv.w;
                }
            }
            float* dst = &sqkv[l * 100 + cc0];
            *(float4*)(dst + 0) = make_float4(acc[0], acc[1], acc[2],  acc[3]);
            *(float4*)(dst + 4) = make_float4(acc[4], acc[5], acc[6],  acc[7]);
            *(float4*)(dst + 8) = make_float4(acc[8], acc[9], acc[10], acc[11]);
        }
        __syncthreads();

        {
            const int h  = tid >> 7;
            const int q  = (tid >> 2) & 31;
            const int kc = tid & 3;
            const int lq = qbase + q;
            const float4* qp = (const float4*)&sqkv[lq * 100 + h * 8];
            float4 q0 = qp[0], q1 = qp[1];
            const float scale = 0.35355339059327373f;

            float sc[16];
#pragma unroll
            for (int jj = 0; jj < 16; ++jj) {
                const int j = kc * 16 + ((jj + kc) & 15);
                const float4* kp = (const float4*)&sqkv[j * 100 + 32 + h * 8];
                sc[jj] = dot8(q0, q1, kp[0], kp[1]) * scale;
            }
            float m0 = fmaxf(fmaxf(fmaxf(sc[0], sc[1]),  fmaxf(sc[2], sc[3])),
                             fmaxf(fmaxf(sc[4], sc[5]),  fmaxf(sc[6], sc[7])));
            float m1 = fmaxf(fmaxf(fmaxf(sc[8], sc[9]),  fmaxf(sc[10], sc[11])),
                             fmaxf(fmaxf(sc[12], sc[13]), fmaxf(sc[14], sc[15])));
            float mx = fmaxf(m0, m1);
            mx = fmaxf(mx, __shfl_xor(mx, 1, 64));
            mx = fmaxf(mx, __shfl_xor(mx, 2, 64));

            float den = 0.f, a[8];
#pragma unroll
            for (int dd = 0; dd < 8; ++dd) a[dd] = 0.f;
#pragma unroll
            for (int jj = 0; jj < 16; ++jj) {
                const int j = kc * 16 + ((jj + kc) & 15);
                float wgt = __expf(sc[jj] - mx);
                den += wgt;
                const float4* vp = (const float4*)&sqkv[j * 100 + 64 + h * 8];
                float4 v0 = vp[0], v1 = vp[1];
                a[0] += wgt * v0.x;  a[1] += wgt * v0.y;
                a[2] += wgt * v0.z;  a[3] += wgt * v0.w;
                a[4] += wgt * v1.x;  a[5] += wgt * v1.y;
                a[6] += wgt * v1.z;  a[7] += wgt * v1.w;
            }
#pragma unroll
            for (int off = 1; off <= 2; off <<= 1) {
                den += __shfl_xor(den, off, 64);
#pragma unroll
                for (int dd = 0; dd < 8; ++dd) a[dd] += __shfl_xor(a[dd], off, 64);
            }
            float inv = 1.f / den;
            float r0, r1;
            if      (kc == 0) { r0 = a[0]; r1 = a[1]; }
            else if (kc == 1) { r0 = a[2]; r1 = a[3]; }
            else if (kc == 2) { r0 = a[4]; r1 = a[5]; }
            else              { r0 = a[6]; r1 = a[7]; }
            so[q * 36 + h * 8 + kc * 2 + 0] = r0 * inv;
            so[q * 36 + h * 8 + kc * 2 + 1] = r1 * inv;
        }
        __syncthreads();

        {
            const int lq2 = tid & 31;
            const int cB  = tid >> 5;
            const int lg  = qbase + lq2;
            const float cvr = chip[b * 64 + lg];
            float orow[32];
            const float4* sop = (const float4*)&so[lq2 * 36];
#pragma unroll
            for (int k4 = 0; k4 < 8; ++k4) {
                float4 t = sop[k4];
                orow[k4 * 4 + 0] = t.x;  orow[k4 * 4 + 1] = t.y;
                orow[k4 * 4 + 2] = t.z;  orow[k4 * 4 + 3] = t.w;
            }
#pragma unroll
            for (int i = 0; i < 2; ++i) {
                int c = cB + i * 16;
                const float4* wr4 = (const float4*)&row_w[c * 32];
                float acc = row_b[c] + (cvr * ew[c] + eb[c] + pe[lg * 32 + c]);
#pragma unroll
                for (int k4 = 0; k4 < 8; ++k4) {
                    float4 wv = wr4[k4];
                    acc += orow[k4 * 4 + 0] * wv.x + orow[k4 * 4 + 1] * wv.y +
                           orow[k4 * 4 + 2] * wv.z + orow[k4 * 4 + 3] * wv.w;
                }
                sqkv[lq2 * 100 + c] = acc;
            }
        }
        __syncthreads();

        {
            const int c = tid & 31;
#pragma unroll
            for (int p = 0; p < 2; ++p) {
                int r = p * 16 + (tid >> 5);
                float v = sqkv[r * 100 + c];
                float s1 = v;
#pragma unroll
                for (int off = 16; off >= 1; off >>= 1) s1 += __shfl_xor(s1, off, 64);
                float mu = s1 * (1.f / 32.f);
                float d = v - mu;
                float s2 = d * d;
#pragma unroll
                for (int off = 16; off >= 1; off >>= 1) s2 += __shfl_xor(s2, off, 64);
                float rstd = rsqrtf(s2 * (1.f / 32.f) + LN_EPS);
                msaR[((b * 4 + s) * 64 + qbase + r) * 32 + c] =
                    d * rstd * rlg[c] + rlb[c];
            }
        }
    }
    grid.sync();

    // ================= Phase 2: column attention =================
    {
        float* sx2   = smem;          // [32][33]
        float* sqkv2 = smem + 1056;   // [32*100]
        float* so2   = smem + 4256;   // [32][36]

        const int b  = bx >> 3;
        const int l0 = (bx & 7) * 8;

        for (int n = tid; n < 1024; n += 512) {
            int r = n >> 5, c = n & 31;
            int lo = r >> 2, s = r & 3;
            sx2[r * 33 + c] = msaR[((b * 4 + s) * 64 + l0 + lo) * 32 + c];
        }
        __syncthreads();

        {
            const int rr = tid & 31;
            const int cg2 = tid >> 5;
            float xr[32];
#pragma unroll
            for (int c = 0; c < 32; ++c) xr[c] = sx2[rr * 33 + c];
#pragma unroll
            for (int i = 0; i < 6; ++i) {
                int cc = i * 16 + cg2;
                const float4* wr4 = (const float4*)&ciw[cc * 32];
                float acc = cib[cc];
#pragma unroll
                for (int c4 = 0; c4 < 8; ++c4) {
                    float4 wv = wr4[c4];
                    acc += xr[c4 * 4 + 0] * wv.x + xr[c4 * 4 + 1] * wv.y +
                           xr[c4 * 4 + 2] * wv.z + xr[c4 * 4 + 3] * wv.w;
                }
                sqkv2[rr * 100 + cc] = acc;
            }
        }
        __syncthreads();

        if (tid < 128) {
            const int lo = tid >> 4, h = (tid >> 2) & 3, ia = tid & 3;
            const float scale = 0.35355339059327373f;
            const float4* qp = (const float4*)&sqkv2[(lo * 4 + ia) * 100 + h * 8];
            float4 q0 = qp[0], q1 = qp[1];
            float sc[4];
            float mx = -1e30f;
#pragma unroll
            for (int jj = 0; jj < 4; ++jj) {
                const float4* kp = (const float4*)&sqkv2[(lo * 4 + jj) * 100 + 32 + h * 8];
                sc[jj] = dot8(q0, q1, kp[0], kp[1]) * scale;
                mx = fmaxf(mx, sc[jj]);
            }
            float den = 0.f;
#pragma unroll
            for (int jj = 0; jj < 4; ++jj) { sc[jj] = __expf(sc[jj] - mx); den += sc[jj]; }
            float inv = 1.f / den;
            float a[8];
#pragma unroll
            for (int dd = 0; dd < 8; ++dd) a[dd] = 0.f;
#pragma unroll
            for (int jj = 0; jj < 4; ++jj) {
                const float4* vp = (const float4*)&sqkv2[(lo * 4 + jj) * 100 + 64 + h * 8];
                float4 v0 = vp[0], v1 = vp[1];
                float wgt = sc[jj];
                a[0] += wgt * v0.x;  a[1] += wgt * v0.y;
                a[2] += wgt * v0.z;  a[3] += wgt * v0.w;
                a[4] += wgt * v1.x;  a[5] += wgt * v1.y;
                a[6] += wgt * v1.z;  a[7] += wgt * v1.w;
            }
#pragma unroll
            for (int dd = 0; dd < 8; ++dd) so2[(lo * 4 + ia) * 36 + h * 8 + dd] = a[dd] * inv;
        }
        __syncthreads();

        {
            const int r2 = tid & 31;
            const int cB = tid >> 5;
            float orow[32];
            const float4* sop = (const float4*)&so2[r2 * 36];
#pragma unroll
            for (int k4 = 0; k4 < 8; ++k4) {
                float4 t = sop[k4];
                orow[k4 * 4 + 0] = t.x;  orow[k4 * 4 + 1] = t.y;
                orow[k4 * 4 + 2] = t.z;  orow[k4 * 4 + 3] = t.w;
            }
#pragma unroll
            for (int i = 0; i < 2; ++i) {
                int c = cB + i * 16;
                const float4* wr4 = (const float4*)&cow[c * 32];
                float acc = cob[c] + sx2[r2 * 33 + c];
#pragma unroll
                for (int k4 = 0; k4 < 8; ++k4) {
                    float4 wv = wr4[k4];
                    acc += orow[k4 * 4 + 0] * wv.x + orow[k4 * 4 + 1] * wv.y +
                           orow[k4 * 4 + 2] * wv.z + orow[k4 * 4 + 3] * wv.w;
                }
                sqkv2[r2 * 100 + c] = acc;
            }
        }
        __syncthreads();

        {
            const int c = tid & 31;
#pragma unroll
            for (int p = 0; p < 2; ++p) {
                int r = p * 16 + (tid >> 5);
                float v = sqkv2[r * 100 + c];
                float s1 = v;
#pragma unroll
                for (int off = 16; off >= 1; off >>= 1) s1 += __shfl_xor(s1, off, 64);
                float mu = s1 * (1.f / 32.f);
                float d = v - mu;
                float s2 = d * d;
#pragma unroll
                for (int off = 16; off >= 1; off >>= 1) s2 += __shfl_xor(s2, off, 64);
                float rstd = rsqrtf(s2 * (1.f / 32.f) + LN_EPS);
                so2[r * 36 + c] = d * rstd;
            }
        }
        __syncthreads();

        if (tid < 256) {
            const int lo = tid >> 5, c = tid & 31;
            float mval = 0.25f * (so2[(lo * 4 + 0) * 36 + c] + so2[(lo * 4 + 1) * 36 + c] +
                                  so2[(lo * 4 + 2) * 36 + c] + so2[(lo * 4 + 3) * 36 + c]) *
                         clg[c] + clb[c];
            mbuf[(b * 64 + l0 + lo) * 32 + c] = mval;
            float q2 = mval * mval;
#pragma unroll
            for (int off = 16; off >= 1; off >>= 1) q2 += __shfl_xor(q2, off, 64);
            if (c == 0) nbuf[b * 64 + l0 + lo] = sqrtf(q2);
        }
    }
}

// ---------------------------------------------------------------------------
// Non-coop fallback for phase 1 (round-3 proven k_row) if coop unavailable.
// ---------------------------------------------------------------------------
__global__ __launch_bounds__(512, 4) void k_row(
    const float* __restrict__ ctcf, const float* __restrict__ hac,
    const float* __restrict__ me1,  const float* __restrict__ me3,
    const float* __restrict__ ew,   const float* __restrict__ eb,
    const float* __restrict__ pe,
    const float* __restrict__ w_in, const float* __restrict__ b_in,
    const float* __restrict__ w_out,const float* __restrict__ b_out,
    const float* __restrict__ ln_g, const float* __restrict__ ln_b,
    float* __restrict__ msaR)
{
    __shared__ float sqkv[64 * 100];
    __shared__ float so[32][36];

    const int blk = blockIdx.x;
    const int qh  = blk & 1;
    const int s   = (blk >> 1) & 3;
    const int b   = blk >> 3;
    const int qbase = qh * 32;
    const int tid = threadIdx.x;

    const float* chip = (s == 0) ? ctcf : (s == 1) ? hac : (s == 2) ? me1 : me3;

    const int l  = tid & 63;
    const int cg = __builtin_amdgcn_readfirstlane(tid >> 6);

    float xr[32];
    {
        const float cv = chip[b * 64 + l];
        const float4* pe4 = (const float4*)&pe[l * 32];
        const float4* ew4 = (const float4*)ew;
        const float4* eb4 = (const float4*)eb;
#pragma unroll
        for (int c4 = 0; c4 < 8; ++c4) {
            float4 pv = pe4[c4], e = ew4[c4], bb = eb4[c4];
            xr[c4 * 4 + 0] = cv * e.x + bb.x + pv.x;
            xr[c4 * 4 + 1] = cv * e.y + bb.y + pv.y;
            xr[c4 * 4 + 2] = cv * e.z + bb.z + pv.z;
            xr[c4 * 4 + 3] = cv * e.w + bb.w + pv.w;
        }
    }

    {
        const int cc0 = cg * 12;
        float acc[12];
#pragma unroll
        for (int ii = 0; ii < 12; ++ii) acc[ii] = b_in[cc0 + ii];
#pragma unroll
        for (int ii = 0; ii < 12; ++ii) {
            const float4* wr4 = (const float4*)&w_in[(cc0 + ii) * 32];
#pragma unroll
            for (int c4 = 0; c4 < 8; ++c4) {
                float4 wv = wr4[c4];
                acc[ii] += xr[c4 * 4 + 0] * wv.x + xr[c4 * 4 + 1] * wv.y +
                           xr[c4 * 4 + 2] * wv.z + xr[c4 * 4 + 3] * wv.w;
            }
        }
        float* dst = &sqkv[l * 100 + cc0];
        *(float4*)(dst + 0) = make_float4(acc[0], acc[1], acc[2],  acc[3]);
        *(float4*)(dst + 4) = make_float4(acc[4], acc[5], acc[6],  acc[7]);
        *(float4*)(dst + 8) = make_float4(acc[8], acc[9], acc[10], acc[11]);
    }
    __syncthreads();

    {
        const int h  = tid >> 7;
        const int q  = (tid >> 2) & 31;
        const int kc = tid & 3;
        const int lq = qbase + q;
        const float4* qp = (const float4*)&sqkv[lq * 100 + h * 8];
        float4 q0 = qp[0], q1 = qp[1];
        const float scale = 0.35355339059327373f;

        float sc[16];
#pragma unroll
        for (int jj = 0; jj < 16; ++jj) {
            const int j = kc * 16 + ((jj + kc) & 15);
            const float4* kp = (const float4*)&sqkv[j * 100 + 32 + h * 8];
            sc[jj] = dot8(q0, q1, kp[0], kp[1]) * scale;
        }
        float m0 = fmaxf(fmaxf(fmaxf(sc[0], sc[1]),  fmaxf(sc[2], sc[3])),
                         fmaxf(fmaxf(sc[4], sc[5]),  fmaxf(sc[6], sc[7])));
        float m1 = fmaxf(fmaxf(fmaxf(sc[8], sc[9]),  fmaxf(sc[10], sc[11])),
                         fmaxf(fmaxf(sc[12], sc[13]), fmaxf(sc[14], sc[15])));
        float mx = fmaxf(m0, m1);
        mx = fmaxf(mx, __shfl_xor(mx, 1, 64));
        mx = fmaxf(mx, __shfl_xor(mx, 2, 64));

        float den = 0.f, a[8];
#pragma unroll
        for (int dd = 0; dd < 8; ++dd) a[dd] = 0.f;
#pragma unroll
        for (int jj = 0; jj < 16; ++jj) {
            const int j = kc * 16 + ((jj + kc) & 15);
            float w = __expf(sc[jj] - mx);
            den += w;
            const float4* vp = (const float4*)&sqkv[j * 100 + 64 + h * 8];
            float4 v0 = vp[0], v1 = vp[1];
            a[0] += w * v0.x;  a[1] += w * v0.y;
            a[2] += w * v0.z;  a[3] += w * v0.w;
            a[4] += w * v1.x;  a[5] += w * v1.y;
            a[6] += w * v1.z;  a[7] += w * v1.w;
        }
#pragma unroll
        for (int off = 1; off <= 2; off <<= 1) {
            den += __shfl_xor(den, off, 64);
#pragma unroll
            for (int dd = 0; dd < 8; ++dd) a[dd] += __shfl_xor(a[dd], off, 64);
        }
        float inv = 1.f / den;
        float r0, r1;
        if      (kc == 0) { r0 = a[0]; r1 = a[1]; }
        else if (kc == 1) { r0 = a[2]; r1 = a[3]; }
        else if (kc == 2) { r0 = a[4]; r1 = a[5]; }
        else              { r0 = a[6]; r1 = a[7]; }
        so[q][h * 8 + kc * 2 + 0] = r0 * inv;
        so[q][h * 8 + kc * 2 + 1] = r1 * inv;
    }
    __syncthreads();

    {
        const int lq2 = tid & 31;
        const int cB  = tid >> 5;
        const int lg  = qbase + lq2;
        const float cvr = chip[b * 64 + lg];
        float orow[32];
        const float4* sop = (const float4*)&so[lq2][0];
#pragma unroll
        for (int k4 = 0; k4 < 8; ++k4) {
            float4 t = sop[k4];
            orow[k4 * 4 + 0] = t.x;  orow[k4 * 4 + 1] = t.y;
            orow[k4 * 4 + 2] = t.z;  orow[k4 * 4 + 3] = t.w;
        }
#pragma unroll
        for (int i = 0; i < 2; ++i) {
            int c = cB + i * 16;
            const float4* wr4 = (const float4*)&w_out[c * 32];
            float acc = b_out[c] + (cvr * ew[c] + eb[c] + pe[lg * 32 + c]);
#pragma unroll
            for (int k4 = 0; k4 < 8; ++k4) {
                float4 wv = wr4[k4];
                acc += orow[k4 * 4 + 0] * wv.x + orow[k4 * 4 + 1] * wv.y +
                       orow[k4 * 4 + 2] * wv.z + orow[k4 * 4 + 3] * wv.w;
            }
            sqkv[lq2 * 100 + c] = acc;
        }
    }
    __syncthreads();

    {
        const int c = tid & 31;
#pragma unroll
        for (int p = 0; p < 2; ++p) {
            int r = p * 16 + (tid >> 5);
            float v = sqkv[r * 100 + c];
            float s1 = v;
#pragma unroll
            for (int off = 16; off >= 1; off >>= 1) s1 += __shfl_xor(s1, off, 64);
            float mu = s1 * (1.f / 32.f);
            float d = v - mu;
            float s2 = d * d;
#pragma unroll
            for (int off = 16; off >= 1; off >>= 1) s2 += __shfl_xor(s2, off, 64);
            float rstd = rsqrtf(s2 * (1.f / 32.f) + LN_EPS);
            msaR[((b * 4 + s) * 64 + qbase + r) * 32 + c] = d * rstd * ln_g[c] + ln_b[c];
        }
    }
}

__global__ __launch_bounds__(256, 4) void k_col(
    const float* __restrict__ msaR,
    const float* __restrict__ w_in, const float* __restrict__ b_in,
    const float* __restrict__ w_out,const float* __restrict__ b_out,
    const float* __restrict__ ln_g, const float* __restrict__ ln_b,
    float* __restrict__ m_out, float* __restrict__ nrm_out)
{
    __shared__ float sx[16][33];
    __shared__ float sqkv[16 * 100];
    __shared__ float so[16][33];

    const int bx = blockIdx.x;
    const int b  = bx >> 4;
    const int l0 = (bx & 15) * 4;
    const int tid = threadIdx.x;

    for (int n = tid; n < 512; n += 256) {
        int r = n >> 5, c = n & 31;
        int lo = r >> 2, s = r & 3;
        sx[r][c] = msaR[((b * 4 + s) * 64 + l0 + lo) * 32 + c];
    }
    __syncthreads();

    {
        const int rr = tid & 15;
        const int cg = tid >> 4;
        float xr[32];
#pragma unroll
        for (int c = 0; c < 32; ++c) xr[c] = sx[rr][c];
#pragma unroll
        for (int i = 0; i < 6; ++i) {
            int cc = i * 16 + cg;
            const float4* wr4 = (const float4*)&w_in[cc * 32];
            float acc = b_in[cc];
#pragma unroll
            for (int c4 = 0; c4 < 8; ++c4) {
                float4 wv = wr4[c4];
                acc += xr[c4 * 4 + 0] * wv.x + xr[c4 * 4 + 1] * wv.y +
                       xr[c4 * 4 + 2] * wv.z + xr[c4 * 4 + 3] * wv.w;
            }
            sqkv[rr * 100 + cc] = acc;
        }
    }
    __syncthreads();

    if (tid < 64) {
        const int lo = tid >> 4, h = (tid >> 2) & 3, ia = tid & 3;
        const float scale = 0.35355339059327373f;
        const float4* qp = (const float4*)&sqkv[(lo * 4 + ia) * 100 + h * 8];
        float4 q0 = qp[0], q1 = qp[1];
        float sc[4];
        float mx = -1e30f;
#pragma unroll
        for (int jj = 0; jj < 4; ++jj) {
            const float4* kp = (const float4*)&sqkv[(lo * 4 + jj) * 100 + 32 + h * 8];
            sc[jj] = dot8(q0, q1, kp[0], kp[1]) * scale;
            mx = fmaxf(mx, sc[jj]);
        }
        float den = 0.f;
#pragma unroll
        for (int jj = 0; jj < 4; ++jj) { sc[jj] = __expf(sc[jj] - mx); den += sc[jj]; }
        float inv = 1.f / den;
        float a[8];
#pragma unroll
        for (int dd = 0; dd < 8; ++dd) a[dd] = 0.f;
#pragma unroll
        for (int jj = 0; jj < 4; ++jj) {
            const float4* vp = (const float4*)&sqkv[(lo * 4 + jj) * 100 + 64 + h * 8];
            float4 v0 = vp[0], v1 = vp[1];
            float wgt = sc[jj];
            a[0] += wgt * v0.x;  a[1] += wgt * v0.y;
            a[2] += wgt * v0.z;  a[3] += wgt * v0.w;
            a[4] += wgt * v1.x;  a[5] += wgt * v1.y;
            a[6] += wgt * v1.z;  a[7] += wgt * v1.w;
        }
#pragma unroll
        for (int dd = 0; dd < 8; ++dd) so[lo * 4 + ia][h * 8 + dd] = a[dd] * inv;
    }
    __syncthreads();

    {
        const int r2 = tid & 15;
        const int cB = tid >> 4;
        float orow[32];
#pragma unroll
        for (int k = 0; k < 32; ++k) orow[k] = so[r2][k];
#pragma unroll
        for (int i = 0; i < 2; ++i) {
            int c = cB + i * 16;
            const float4* wr4 = (const float4*)&w_out[c * 32];
            float acc = b_out[c] + sx[r2][c];
#pragma unroll
            for (int k4 = 0; k4 < 8; ++k4) {
                float4 wv = wr4[k4];
                acc += orow[k4 * 4 + 0] * wv.x + orow[k4 * 4 + 1] * wv.y +
                       orow[k4 * 4 + 2] * wv.z + orow[k4 * 4 + 3] * wv.w;
            }
            sqkv[r2 * 100 + c] = acc;
        }
    }
    __syncthreads();

    {
        const int c = tid & 31;
#pragma unroll
        for (int p = 0; p < 2; ++p) {
            int r = p * 8 + (tid >> 5);
            float v = sqkv[r * 100 + c];
            float s1 = v;
#pragma unroll
            for (int off = 16; off >= 1; off >>= 1) s1 += __shfl_xor(s1, off, 64);
            float mu = s1 * (1.f / 32.f);
            float d = v - mu;
            float s2 = d * d;
#pragma unroll
            for (int off = 16; off >= 1; off >>= 1) s2 += __shfl_xor(s2, off, 64);
            float rstd = rsqrtf(s2 * (1.f / 32.f) + LN_EPS);
            so[r][c] = d * rstd;
        }
    }
    __syncthreads();

    if (tid < 128) {
        const int lo = tid >> 5, c = tid & 31;
        float mval = 0.25f * (so[lo * 4 + 0][c] + so[lo * 4 + 1][c] +
                              so[lo * 4 + 2][c] + so[lo * 4 + 3][c]) * ln_g[c] + ln_b[c];
        m_out[(b * 64 + l0 + lo) * 32 + c] = mval;
        float q2 = mval * mval;
#pragma unroll
        for (int off = 16; off >= 1; off >>= 1) q2 += __shfl_xor(q2, off, 64);
        if (c == 0) nrm_out[b * 64 + l0 + lo] = sqrtf(q2);
    }
}

// ---------------------------------------------------------------------------
// Phase 3: standalone (non-coop). Round-3 proven form: 1024 x 256.
// ---------------------------------------------------------------------------
__global__ __launch_bounds__(256, 4) void k_pair(
    const float* __restrict__ m, const float* __restrict__ nrm,
    const float* __restrict__ pw, const float* __restrict__ pb,
    const float* __restrict__ pg, const float* __restrict__ pbeta,
    float* __restrict__ out)
{
    __shared__ float smj[64][36];
    __shared__ float sT[4 * 520];
    __shared__ float snj[64];
    __shared__ float sbias[16], sgam[16], sbet[16];

    const int bx = blockIdx.x;
    const int b  = bx >> 4;
    const int i0 = (bx & 15) * 4;
    const int tid = threadIdx.x;
    const int lane = tid & 63, w = tid >> 6;

    const int rem0 = tid, rem1 = tid + 256;
    const float* pw0 = pw + (rem0 >> 5) * 1024 + (rem0 & 31);
    const float* pw1 = pw + (rem1 >> 5) * 1024 + (rem1 & 31);
    float w0[32], w1[32];
#pragma unroll
    for (int c = 0; c < 32; ++c) { w0[c] = pw0[c * 32]; w1[c] = pw1[c * 32]; }

    const float* mb = m + b * 2048;
    for (int n = tid; n < 2048; n += 256) smj[n >> 5][n & 31] = mb[n];
    if (tid < 64) snj[tid] = nrm[b * 64 + tid];
    if (tid < 16) {
        sbias[tid] = pb[tid];
        sgam[tid]  = pg[tid];
        sbet[tid]  = pbeta[tid];
    }
    __syncthreads();

#pragma unroll
    for (int il = 0; il < 4; ++il) {
        const float4* mr4 = (const float4*)&smj[i0 + il][0];
        float a0 = 0.f, a1 = 0.f;
#pragma unroll
        for (int c4 = 0; c4 < 8; ++c4) {
            float4 mv = mr4[c4];
            a0 += mv.x * w0[c4 * 4 + 0] + mv.y * w0[c4 * 4 + 1] +
                  mv.z * w0[c4 * 4 + 2] + mv.w * w0[c4 * 4 + 3];
            a1 += mv.x * w1[c4 * 4 + 0] + mv.y * w1[c4 * 4 + 1] +
                  mv.z * w1[c4 * 4 + 2] + mv.w * w1[c4 * 4 + 3];
        }
        sT[il * 520 + rem0] = a0;
        sT[il * 520 + rem1] = a1;
    }
    __syncthreads();

    const int j = lane;
    float mj[32];
    {
        const float4* mjp = (const float4*)&smj[j][0];
#pragma unroll
        for (int d4 = 0; d4 < 8; ++d4) {
            float4 t = mjp[d4];
            mj[d4 * 4 + 0] = t.x;  mj[d4 * 4 + 1] = t.y;
            mj[d4 * 4 + 2] = t.z;  mj[d4 * 4 + 3] = t.w;
        }
    }
    const float nj = snj[j];

    {
        const int il = w;
        const int ig = i0 + il;
        const float invn = 1.f / fmaxf(snj[ig] * nj, 1e-6f);
        float f[16];
#pragma unroll
        for (int cp = 0; cp < 16; ++cp) {
            const float4* tr = (const float4*)&sT[il * 520 + cp * 32];
            float acc = 0.f;
#pragma unroll
            for (int d4 = 0; d4 < 8; ++d4) {
                float4 tv = tr[d4];
                acc += tv.x * mj[d4 * 4 + 0] + tv.y * mj[d4 * 4 + 1] +
                       tv.z * mj[d4 * 4 + 2] + tv.w * mj[d4 * 4 + 3];
            }
            f[cp] = acc * invn + sbias[cp];
        }
        float mu = 0.f;
#pragma unroll
        for (int cp = 0; cp < 16; ++cp) mu += f[cp];
        mu *= (1.f / 16.f);
        float var = 0.f;
#pragma unroll
        for (int cp = 0; cp < 16; ++cp) { float d = f[cp] - mu; var += d * d; }
        var *= (1.f / 16.f);
        const float rstd = rsqrtf(var + LN_EPS);
#pragma unroll
        for (int cp = 0; cp < 16; ++cp) {
            float v = (f[cp] - mu) * rstd * sgam[cp] + sbet[cp];
            float sl = v / (1.f + __expf(-v));
            out[((b * 16 + cp) * 64 + ig) * 64 + j] = sl;
        }
    }
}

// ---------------------------------------------------------------------------
extern "C" void kernel_launch(void* const* d_in, const int* in_sizes, int n_in,
                              void* d_out, int out_size, void* d_ws, size_t ws_size,
                              hipStream_t stream) {
    const float* ctcf  = (const float*)d_in[0];
    const float* hac   = (const float*)d_in[1];
    const float* me1   = (const float*)d_in[2];
    const float* me3   = (const float*)d_in[3];
    const float* ew    = (const float*)d_in[4];
    const float* ebias = (const float*)d_in[5];
    const float* pe    = (const float*)d_in[6];
    const float* riw   = (const float*)d_in[7];
    const float* rib   = (const float*)d_in[8];
    const float* row_  = (const float*)d_in[9];
    const float* rob   = (const float*)d_in[10];
    const float* rlg   = (const float*)d_in[11];
    const float* rlb   = (const float*)d_in[12];
    const float* ciw   = (const float*)d_in[13];
    const float* cib   = (const float*)d_in[14];
    const float* cow   = (const float*)d_in[15];
    const float* cob   = (const float*)d_in[16];
    const float* clg   = (const float*)d_in[17];
    const float* clb   = (const float*)d_in[18];
    const float* pw    = (const float*)d_in[19];
    const float* pb    = (const float*)d_in[20];
    const float* pg    = (const float*)d_in[21];
    const float* pbt   = (const float*)d_in[22];

    float* outp = (float*)d_out;

    float* msaR = (float*)d_out;                 // borrowed; consumed pre-k_pair
    float* mbuf = (float*)d_ws;                  // 64*64*32 floats
    float* nbuf = mbuf + 64 * 64 * 32;           // 64*64 floats

    static int s_coop = -1;
    if (s_coop < 0) {
        int nb = 0;
        hipError_t e = hipOccupancyMaxActiveBlocksPerMultiprocessor(
            &nb, k12, 512, 0);
        s_coop = (e == hipSuccess && nb >= 2) ? 1 : 0;
    }

    bool done12 = false;
    if (s_coop) {
        void* args[] = {
            (void*)&ctcf, (void*)&hac, (void*)&me1, (void*)&me3,
            (void*)&ew,   (void*)&ebias, (void*)&pe,
            (void*)&riw,  (void*)&rib, (void*)&row_, (void*)&rob,
            (void*)&rlg,  (void*)&rlb,
            (void*)&ciw,  (void*)&cib, (void*)&cow, (void*)&cob,
            (void*)&clg,  (void*)&clb,
            (void*)&msaR, (void*)&mbuf, (void*)&nbuf
        };
        hipError_t le = hipLaunchCooperativeKernel((void*)k12, dim3(512),
                                                   dim3(512), args, 0, stream);
        if (le == hipSuccess) done12 = true; else s_coop = 0;
    }
    if (!done12) {
        k_row<<<512, 512, 0, stream>>>(ctcf, hac, me1, me3, ew, ebias, pe,
                                       riw, rib, row_, rob, rlg, rlb, msaR);
        k_col<<<1024, 256, 0, stream>>>(msaR, ciw, cib, cow, cob, clg, clb,
                                        mbuf, nbuf);
    }
    k_pair<<<1024, 256, 0, stream>>>(mbuf, nbuf, pw, pb, pg, pbt, outp);
}